// Round 5
// baseline (152.696 us; speedup 1.0000x reference)
//
#include <hip/hip_runtime.h>
#include <math.h>

#define EPSBN 1e-5f
#define AADD(p, v) __hip_atomic_fetch_add((p), (v), __ATOMIC_RELAXED, __HIP_MEMORY_SCOPE_AGENT)

typedef unsigned short u16;
typedef short bf16x8 __attribute__((ext_vector_type(8)));
typedef float f32x4 __attribute__((ext_vector_type(4)));
typedef float f32x16 __attribute__((ext_vector_type(16)));
typedef int i32x4 __attribute__((ext_vector_type(4)));

constexpr int NROWS = 8192;
constexpr int NCLS = 10;
constexpr int MPAD = 8832;        // 138 tiles of 64
constexpr int NT_PAD = 138;
constexpr int GY = 8;             // balanced groups of 17/18 tiles
constexpr float SCL  = 2.0813689810056077f;   // (log2 e)^2
constexpr float SCL2 = -4.1627379620112154f;  // -2*(log2 e)^2

// workspace offsets (floats)
constexpr size_t OFF_W0P = 0;                      // u16[65536]
constexpr size_t OFF_H1H = 32768;                  // u16[16384*128]
constexpr size_t OFF_H1L = OFF_H1H + 1048576;
constexpr size_t OFF_SUM = OFF_H1L + 1048576;      // 768 floats
constexpr size_t OFF_W1P = OFF_SUM + 768;          // u16[32768]
constexpr size_t OFF_B1E = OFF_W1P + 16384;        // 128
constexpr size_t OFF_H2  = OFF_B1E + 128;          // 16384*64 floats
constexpr size_t OFF_PIDX = OFF_H2 + 1048576;      // int[8832]
constexpr size_t OFF_TCLS = OFF_PIDX + MPAD;       // int[144]
// overlays over h1 (dead after layer2)
constexpr size_t OFF_QH  = OFF_H1H;                // u16[8192*64]
constexpr size_t OFF_QL  = OFF_QH + 262144;
constexpr size_t OFF_QN2 = OFF_QL + 262144;        // 8192 f
constexpr size_t OFF_KH  = OFF_QN2 + NROWS;        // u16[8832*64]
constexpr size_t OFF_KL  = OFF_KH + 282624;
constexpr size_t OFF_KN2 = OFF_KL + 282624;        // 8832 f
// part over h2 (dead after bn2): 8*11*8192 = 720896 <= 1048576
constexpr size_t OFF_PART = OFF_H2;

__device__ inline u16 f2bf(float f) {
  unsigned u = __float_as_uint(f);
  unsigned r = (u + 0x7fffu + ((u >> 16) & 1u)) >> 16;
  return (u16)r;
}
__device__ inline float bf2f(u16 h) { return __uint_as_float(((unsigned)h) << 16); }

__device__ inline float tanh_fast(float x) {
  float e = __builtin_amdgcn_exp2f(x * 2.88539008f);
  return 1.f - 2.f * __builtin_amdgcn_rcpf(e + 1.f);
}

// async global->LDS, 16B per lane; dest = wave-uniform base + lane*16
__device__ inline void glds16(const u16* g, u16* l) {
  __builtin_amdgcn_global_load_lds(
      (const __attribute__((address_space(1))) unsigned int*)g,
      (__attribute__((address_space(3))) unsigned int*)l, 16, 0, 0);
}

// ---------------- prep: W0 pack (blocks 0-127) + sort + zero sums (block 128) --------
__global__ __launch_bounds__(256) void k_prep(
    const float* __restrict__ w0, const int* __restrict__ yn,
    u16* __restrict__ w0p, int* __restrict__ pidx, int* __restrict__ tcls,
    float* __restrict__ sums)
{
  if (blockIdx.x < 128) {
    int idx = blockIdx.x * 256 + threadIdx.x;   // 32768
    int t = idx & 255;
    float v = w0[idx];
    u16 hi = f2bf(v);
    u16 lo = f2bf(v - bf2f(hi));
    int j = idx >> 8;
    w0p[(t >> 3) * 1024 + j * 8 + (t & 7)] = hi;
    w0p[32768 + (t >> 3) * 1024 + j * 8 + (t & 7)] = lo;
    return;
  }
  __shared__ int cnt[256][NCLS];
  __shared__ int wtot[4][NCLS];
  __shared__ int pstart[NCLS + 1];
  const int t = threadIdx.x;
  const int lane = t & 63, wv = t >> 6;
  sums[t] = 0.f; sums[t + 256] = 0.f; sums[t + 512] = 0.f;
  #pragma unroll
  for (int c = 0; c < NCLS; ++c) cnt[t][c] = 0;
  for (int i = t; i < MPAD; i += 256) pidx[i] = -1;
  for (int i = t; i < NROWS; i += 256) cnt[t][yn[i]]++;
  __syncthreads();
  #pragma unroll
  for (int c = 0; c < NCLS; ++c) {
    int x = cnt[t][c];
    int inc = x;
    #pragma unroll
    for (int d = 1; d < 64; d <<= 1) { int y = __shfl_up(inc, d); if (lane >= d) inc += y; }
    if (lane == 63) wtot[wv][c] = inc;
    cnt[t][c] = inc - x;
  }
  __syncthreads();
  if (t == 0) {
    int run = 0;
    #pragma unroll
    for (int c = 0; c < NCLS; ++c) {
      int tot = wtot[0][c] + wtot[1][c] + wtot[2][c] + wtot[3][c];
      pstart[c] = run;
      int ntile = (tot + 63) >> 6;
      for (int tt = 0; tt < ntile; ++tt) tcls[(run >> 6) + tt] = c;
      run += ntile << 6;
    }
    pstart[NCLS] = run;
    for (int tt = run >> 6; tt < NT_PAD; ++tt) tcls[tt] = NCLS;
  }
  __syncthreads();
  #pragma unroll
  for (int c = 0; c < NCLS; ++c) {
    int add = pstart[c];
    for (int w2 = 0; w2 < 4; ++w2) if (w2 < wv) add += wtot[w2][c];
    cnt[t][c] += add;
  }
  __syncthreads();
  for (int i = t; i < NROWS; i += 256) {
    int c = yn[i];
    pidx[cnt[t][c]++] = i;
  }
}

// ---------------- layer 1: MFMA, split-bf16 3-pass, atomic BN stats ----------------
__global__ __launch_bounds__(256) void k_layer1(
    const float* __restrict__ x, const float* __restrict__ xn,
    const u16* __restrict__ w0p, const float* __restrict__ b0,
    u16* __restrict__ h1h, u16* __restrict__ h1l, float* __restrict__ sums)
{
  const int tid = threadIdx.x;
  const int w = tid >> 6, l = tid & 63;
  const int l15 = l & 15, l4 = l >> 4;
  const int blk = blockIdx.x;                 // 512
  const int rowHalf = w & 1, colHalf = w >> 1;
  const int r0 = blk * 32 + 16 * rowHalf;
  const int c0 = 64 * colHalf;
  const int b = (blk < 256) ? 0 : 1;
  const float* src = (blk < 256) ? (x + (size_t)blk * 32 * 256)
                                 : (xn + (size_t)(blk - 256) * 32 * 256);
  const float* xrow = src + (size_t)(16 * rowHalf + l15) * 256;

  f32x4 acc[4];
  #pragma unroll
  for (int ct = 0; ct < 4; ++ct) acc[ct] = (f32x4){0.f, 0.f, 0.f, 0.f};

  #pragma unroll
  for (int ks = 0; ks < 8; ++ks) {
    const float* xp = xrow + ks * 32 + l4 * 8;
    f32x4 a0 = *(const f32x4*)xp;
    f32x4 a1 = *(const f32x4*)(xp + 4);
    bf16x8 ah, al_;
    #pragma unroll
    for (int i = 0; i < 4; ++i) {
      u16 h = f2bf(a0[i]); ah[i] = (short)h; al_[i] = (short)f2bf(a0[i] - bf2f(h));
    }
    #pragma unroll
    for (int i = 0; i < 4; ++i) {
      u16 h = f2bf(a1[i]); ah[4 + i] = (short)h; al_[4 + i] = (short)f2bf(a1[i] - bf2f(h));
    }
    const u16* bbase = w0p + (size_t)(ks * 4 + l4) * 1024;
    #pragma unroll
    for (int ct = 0; ct < 4; ++ct) {
      const int col = c0 + 16 * ct + l15;
      bf16x8 bh = *(const bf16x8*)(bbase + col * 8);
      bf16x8 bl = *(const bf16x8*)(bbase + 32768 + col * 8);
      acc[ct] = __builtin_amdgcn_mfma_f32_16x16x32_bf16(ah, bh, acc[ct], 0, 0, 0);
      acc[ct] = __builtin_amdgcn_mfma_f32_16x16x32_bf16(ah, bl, acc[ct], 0, 0, 0);
      acc[ct] = __builtin_amdgcn_mfma_f32_16x16x32_bf16(al_, bh, acc[ct], 0, 0, 0);
    }
  }

  #pragma unroll
  for (int ct = 0; ct < 4; ++ct) {
    const int col = c0 + 16 * ct + l15;
    const float bj = b0[col];
    float s = 0.f, q = 0.f;
    #pragma unroll
    for (int r = 0; r < 4; ++r) {
      float v = tanh_fast(acc[ct][r] + bj);
      const int row = r0 + 4 * l4 + r;
      u16 hi = f2bf(v);
      h1h[(size_t)row * 128 + col] = hi;
      h1l[(size_t)row * 128 + col] = f2bf(v - bf2f(hi));
      s += v; q += v * v;
    }
    s += __shfl_xor(s, 16); s += __shfl_xor(s, 32);
    q += __shfl_xor(q, 16); q += __shfl_xor(q, 32);
    if (l < 16) {
      AADD(&sums[b * 128 + col], s);
      AADD(&sums[256 + b * 128 + col], q);
    }
  }
}

// ---- parallel fold: BN1 scale/shift from sums -> packed W1eff + eff bias ----
__global__ __launch_bounds__(128) void k_foldp(
    const float* __restrict__ w1, const float* __restrict__ b1,
    const float* __restrict__ g0, const float* __restrict__ bt0,
    const float* __restrict__ sums, u16* __restrict__ w1p, float* __restrict__ b1e)
{
  const int o = blockIdx.x;          // 64
  const int j = threadIdx.x;         // 128
  __shared__ float red[2][2];
  const float w = w1[o * 128 + j];
  #pragma unroll
  for (int b = 0; b < 2; ++b) {
    float s = sums[b * 128 + j], q = sums[256 + b * 128 + j];
    float m = s * (1.f / 8192.f);
    float v = q * (1.f / 8192.f) - m * m;
    float sc = g0[j] * rsqrtf(v + EPSBN);
    float sh = bt0[j] - m * sc;
    float wsc = w * sc;
    u16 hi = f2bf(wsc);
    u16 lo = f2bf(wsc - bf2f(hi));
    w1p[((size_t)(b * 2 + 0) * 16 + (j >> 3)) * 512 + o * 8 + (j & 7)] = hi;
    w1p[((size_t)(b * 2 + 1) * 16 + (j >> 3)) * 512 + o * 8 + (j & 7)] = lo;
    float a = w * sh;
    #pragma unroll
    for (int off = 32; off; off >>= 1) a += __shfl_xor(a, off);
    if ((j & 63) == 0) red[j >> 6][b] = a;
  }
  __syncthreads();
  if (j < 2) b1e[j * 64 + o] = b1[o] + red[0][j] + red[1][j];
}

// ---------------- layer 2: MFMA, split-bf16 3-pass, atomic BN stats ----------------
__global__ __launch_bounds__(256) void k_layer2(
    const u16* __restrict__ h1h, const u16* __restrict__ h1l,
    const u16* __restrict__ w1p, const float* __restrict__ b1e,
    float* __restrict__ h2, float* __restrict__ sums)
{
  const int tid = threadIdx.x;
  const int w = tid >> 6, l = tid & 63;
  const int l15 = l & 15, l4 = l >> 4;
  const int blk = blockIdx.x;                 // 512
  const int rowHalf = w & 1, colHalf = w >> 1;
  const int r0 = blk * 32 + 16 * rowHalf;
  const int c0 = 32 * colHalf;
  const int b = blk >> 8;
  const u16* arow_h = h1h + (size_t)(r0 + l15) * 128;
  const u16* arow_l = h1l + (size_t)(r0 + l15) * 128;

  f32x4 acc[2];
  acc[0] = (f32x4){0.f, 0.f, 0.f, 0.f};
  acc[1] = (f32x4){0.f, 0.f, 0.f, 0.f};

  #pragma unroll
  for (int ks = 0; ks < 4; ++ks) {
    bf16x8 ah = *(const bf16x8*)(arow_h + ks * 32 + l4 * 8);
    bf16x8 al_ = *(const bf16x8*)(arow_l + ks * 32 + l4 * 8);
    const u16* bb = w1p + ((size_t)(b * 2) * 16 + ks * 4 + l4) * 512;
    #pragma unroll
    for (int ct = 0; ct < 2; ++ct) {
      const int col = c0 + 16 * ct + l15;
      bf16x8 bh = *(const bf16x8*)(bb + col * 8);
      bf16x8 bl = *(const bf16x8*)(bb + 8192 + col * 8);
      acc[ct] = __builtin_amdgcn_mfma_f32_16x16x32_bf16(ah, bh, acc[ct], 0, 0, 0);
      acc[ct] = __builtin_amdgcn_mfma_f32_16x16x32_bf16(ah, bl, acc[ct], 0, 0, 0);
      acc[ct] = __builtin_amdgcn_mfma_f32_16x16x32_bf16(al_, bh, acc[ct], 0, 0, 0);
    }
  }

  #pragma unroll
  for (int ct = 0; ct < 2; ++ct) {
    const int col = c0 + 16 * ct + l15;
    const float bj = b1e[b * 64 + col];
    float s = 0.f, q = 0.f;
    #pragma unroll
    for (int r = 0; r < 4; ++r) {
      float v = tanh_fast(acc[ct][r] + bj);
      const int row = r0 + 4 * l4 + r;
      h2[(size_t)row * 64 + col] = v;
      s += v; q += v * v;
    }
    s += __shfl_xor(s, 16); s += __shfl_xor(s, 32);
    q += __shfl_xor(q, 16); q += __shfl_xor(q, 32);
    if (l < 16) {
      AADD(&sums[512 + b * 64 + col], s);
      AADD(&sums[640 + b * 64 + col], q);
    }
  }
}

// ---------------- BN2 (inline scale from sums) + bf16 split, norms pre-scaled ------
__global__ __launch_bounds__(256) void k_bn2(
    const float* __restrict__ h2, const float* __restrict__ sums,
    const float* __restrict__ g1, const float* __restrict__ bt1,
    const int* __restrict__ pidx,
    u16* __restrict__ qh, u16* __restrict__ ql, float* __restrict__ qn2,
    u16* __restrict__ kh, u16* __restrict__ kl, float* __restrict__ kn2)
{
  const int tid = threadIdx.x;
  const int r = tid >> 6, o = tid & 63;
  const bool isq = (blockIdx.x < 2048);
  const int b = isq ? 0 : 1;
  float s = sums[512 + b * 64 + o], q = sums[640 + b * 64 + o];
  float m = s * (1.f / 8192.f);
  float v = q * (1.f / 8192.f) - m * m;
  float sc = g1[o] * rsqrtf(v + EPSBN);
  float sh = bt1[o] - m * sc;
  if (isq) {
    const int row = blockIdx.x * 4 + r;
    float vv = sc * h2[(size_t)row * 64 + o] + sh;
    u16 hi = f2bf(vv);
    qh[(size_t)row * 64 + o] = hi;
    ql[(size_t)row * 64 + o] = f2bf(vv - bf2f(hi));
    float sq = vv * vv;
    #pragma unroll
    for (int off = 32; off; off >>= 1) sq += __shfl_xor(sq, off);
    if (o == 0) qn2[row] = SCL * sq;
  } else {
    const int row = (blockIdx.x - 2048) * 4 + r;   // 0..8831
    const int src = pidx[row];
    float vv = 0.f;
    if (src >= 0) vv = sc * h2[(size_t)(NROWS + src) * 64 + o] + sh;
    u16 hi = f2bf(vv);
    kh[(size_t)row * 64 + o] = hi;
    kl[(size_t)row * 64 + o] = f2bf(vv - bf2f(hi));
    float sq = vv * vv;
    #pragma unroll
    for (int off = 32; off; off >>= 1) sq += __shfl_xor(sq, off);
    if (o == 0) kn2[row] = (src >= 0) ? SCL * sq : 1e30f;
  }
}

// ---------------- cdist: 32x32x16 MFMA, dbuf LDS, glds staging, 2 acc chains -------
__global__ __launch_bounds__(256, 4) void k_dist(
    const u16* __restrict__ qh, const u16* __restrict__ ql, const float* __restrict__ qn2,
    const u16* __restrict__ kh, const u16* __restrict__ kl, const float* __restrict__ kn2,
    const int* __restrict__ tcls, float* __restrict__ part)
{
  __shared__ u16 bs[2][8192];                       // 2 x 16 KB
  __shared__ float cls_lds[2 * (NCLS + 1) * 64];    // per-colHalf copies
  const int tid = threadIdx.x;
  const int w = tid >> 6, l = tid & 63;
  const int n0 = blockIdx.x * 64;
  const int g = blockIdx.y;
  const int t0 = (g * NT_PAD) / GY, t1 = ((g + 1) * NT_PAD) / GY;

  for (int i = tid; i < 2 * (NCLS + 1) * 64; i += 256) cls_lds[i] = 0.f;

  // ---- A fragments (q rows, in regs all kernel) ----
  const int lh = l >> 5;
  const int arow = n0 + 32 * (w >> 1) + (l & 31);
  bf16x8 aH[4], aL[4];
  #pragma unroll
  for (int j = 0; j < 4; ++j) {
    aH[j] = *(const bf16x8*)(qh + (size_t)arow * 64 + j * 16 + 8 * lh);
    aL[j] = *(const bf16x8*)(ql + (size_t)arow * 64 + j * 16 + 8 * lh);
  }
  float qnr[16];
  #pragma unroll
  for (int g4 = 0; g4 < 4; ++g4) {
    f32x4 qv = *(const f32x4*)(qn2 + n0 + 32 * (w >> 1) + 8 * g4 + 4 * lh);
    qnr[4 * g4 + 0] = qv[0]; qnr[4 * g4 + 1] = qv[1];
    qnr[4 * g4 + 2] = qv[2]; qnr[4 * g4 + 3] = qv[3];
  }

  // ---- staging via global_load_lds: instr j fills LDS bytes [(w*4+j)*1024 .. +1KB)
  // content invariant: byte col*256 + a*128 + s*16 holds {arr a, row m0+col, chunk s^(col&7)}
  // lane l of instr j -> LDS slot: col=16w+4j+(l>>4), a=(l>>3)&1, s=l&7
  const int a_ = (l >> 3) & 1;
  const u16* sarr = a_ ? kl : kh;
  int soff[4];
  #pragma unroll
  for (int j = 0; j < 4; ++j) {
    const int col = 16 * w + 4 * j + (l >> 4);
    const int c8 = (l & 7) ^ (col & 7);
    soff[j] = col * 64 + c8 * 8;          // u16 units, row m0 added per tile
  }

  // ---- B-read ids: wave w computes rows 32*(w>>1), cols 32*(w&1) ----
  const int colL = 32 * (w & 1) + (l & 31);
  const char* rb_base = (const char*)&bs[0][0] + colL * 256;
  const int c7r = colL & 7;

#define STAGE(TT, PB) do { const size_t tb_ = (size_t)(TT) * 4096; \
    u16* lb_ = &bs[PB][0] + (size_t)(w * 4) * 512; \
    glds16(sarr + tb_ + soff[0], lb_);        \
    glds16(sarr + tb_ + soff[1], lb_ + 512);  \
    glds16(sarr + tb_ + soff[2], lb_ + 1024); \
    glds16(sarr + tb_ + soff[3], lb_ + 1536); } while (0)

#define FLUSH(CC) do { \
    _Pragma("unroll") for (int r = 0; r < 16; ++r) { \
      run[r] += __shfl_xor(run[r], 1);  run[r] += __shfl_xor(run[r], 2); \
      run[r] += __shfl_xor(run[r], 4);  run[r] += __shfl_xor(run[r], 8); \
      run[r] += __shfl_xor(run[r], 16); } \
    if ((l & 31) == 0) { \
      float* cl_ = cls_lds + (w & 1) * 704 + (CC) * 64 + 32 * (w >> 1) + 4 * lh; \
      _Pragma("unroll") for (int r = 0; r < 16; ++r) cl_[(r & 3) + 8 * (r >> 2)] += run[r]; } \
    _Pragma("unroll") for (int r = 0; r < 16; ++r) run[r] = 0.f; } while (0)

  STAGE(t0, 0);

  float run[16];
  #pragma unroll
  for (int r = 0; r < 16; ++r) run[r] = 0.f;
  int ccur = tcls[t0];
  int p = 0;

  for (int t = t0; t < t1; ++t) {
    __syncthreads();                       // drains vmcnt -> buf[p] staged; p^1 readers done
    if (t + 1 < t1) STAGE(t + 1, p ^ 1);
    const int c = tcls[t];
    if (c != ccur) { FLUSH(ccur); ccur = c; }
    const float kv = kn2[t * 64 + colL];

    f32x16 accA, accB;
    #pragma unroll
    for (int r = 0; r < 16; ++r) { accA[r] = 0.f; accB[r] = 0.f; }
    const char* pb = rb_base + p * 16384;
    #pragma unroll
    for (int j = 0; j < 4; ++j) {
      const int c8 = 2 * j + lh;
      bf16x8 bh  = *(const bf16x8*)(pb + ((c8 ^ c7r) << 4));
      bf16x8 bl_ = *(const bf16x8*)(pb + 128 + ((c8 ^ c7r) << 4));
      accA = __builtin_amdgcn_mfma_f32_32x32x16_bf16(aH[j], bh,  accA, 0, 0, 0);
      accB = __builtin_amdgcn_mfma_f32_32x32x16_bf16(aH[j], bl_, accB, 0, 0, 0);
      accA = __builtin_amdgcn_mfma_f32_32x32x16_bf16(aL[j], bh,  accA, 0, 0, 0);
    }
    #pragma unroll
    for (int r = 0; r < 16; ++r) {
      float d2 = fmaf(SCL2, accA[r] + accB[r], qnr[r] + kv);
      d2 = fmaxf(d2, 2.0813689e-12f);
      run[r] += __builtin_amdgcn_exp2f(-__builtin_amdgcn_sqrtf(d2));
    }
    p ^= 1;
  }
  FLUSH(ccur);
  __syncthreads();

  for (int i = tid; i < (NCLS + 1) * 64; i += 256) {
    const int c = i >> 6, rr = i & 63;
    part[((size_t)g * (NCLS + 1) + c) * NROWS + n0 + rr] = cls_lds[i] + cls_lds[704 + i];
  }
#undef STAGE
#undef FLUSH
}

// ---- finalize ----
__global__ __launch_bounds__(256) void k_final(const float* __restrict__ part,
                                               float* __restrict__ out)
{
  const int n = blockIdx.x * 256 + threadIdx.x;
  float sc[NCLS];
  #pragma unroll
  for (int c = 0; c < NCLS; ++c) sc[c] = 0.f;
  for (int g = 0; g < GY; ++g) {
    #pragma unroll
    for (int c = 0; c < NCLS; ++c)
      sc[c] += part[((size_t)g * (NCLS + 1) + c) * NROWS + n];
  }
  float tot = 0.f;
  #pragma unroll
  for (int c = 0; c < NCLS; ++c) tot += sc[c];
  const float inv = 1.f / tot;
  #pragma unroll
  for (int c = 0; c < NCLS; ++c)
    out[(size_t)n * NCLS + c] = fminf(fmaxf(sc[c] * inv, 0.f), 1.f);
}

extern "C" void kernel_launch(void* const* d_in, const int* in_sizes, int n_in,
                              void* d_out, int out_size, void* d_ws, size_t ws_size,
                              hipStream_t stream) {
  const float* x   = (const float*)d_in[0];
  const float* xn  = (const float*)d_in[1];
  const int*   yn  = (const int*)d_in[2];
  const float* W0  = (const float*)d_in[3];
  const float* b0  = (const float*)d_in[4];
  const float* g0  = (const float*)d_in[5];
  const float* bt0 = (const float*)d_in[6];
  const float* W1  = (const float*)d_in[7];
  const float* b1  = (const float*)d_in[8];
  const float* g1  = (const float*)d_in[9];
  const float* bt1 = (const float*)d_in[10];
  float* out = (float*)d_out;
  float* ws  = (float*)d_ws;

  u16*   w0pp = (u16*)(ws + OFF_W0P);
  u16*   h1hp = (u16*)(ws + OFF_H1H);
  u16*   h1lp = (u16*)(ws + OFF_H1L);
  float* sumsp= ws + OFF_SUM;
  u16*   w1pp = (u16*)(ws + OFF_W1P);
  float* b1ep = ws + OFF_B1E;
  float* h2p  = ws + OFF_H2;
  int*   pidxp= (int*)(ws + OFF_PIDX);
  int*   tclsp= (int*)(ws + OFF_TCLS);
  u16*   qhp  = (u16*)(ws + OFF_QH);
  u16*   qlp  = (u16*)(ws + OFF_QL);
  float* qn2p = ws + OFF_QN2;
  u16*   khp  = (u16*)(ws + OFF_KH);
  u16*   klp  = (u16*)(ws + OFF_KL);
  float* kn2p = ws + OFF_KN2;
  float* partp= ws + OFF_PART;

  k_prep<<<129, 256, 0, stream>>>(W0, yn, w0pp, pidxp, tclsp, sumsp);
  k_layer1<<<512, 256, 0, stream>>>(x, xn, w0pp, b0, h1hp, h1lp, sumsp);
  k_foldp<<<64, 128, 0, stream>>>(W1, b1, g0, bt0, sumsp, w1pp, b1ep);
  k_layer2<<<512, 256, 0, stream>>>(h1hp, h1lp, w1pp, b1ep, h2p, sumsp);
  k_bn2<<<2048 + MPAD / 4, 256, 0, stream>>>(h2p, sumsp, g1, bt1, pidxp,
                                             qhp, qlp, qn2p, khp, klp, kn2p);
  k_dist<<<dim3(128, GY), 256, 0, stream>>>(qhp, qlp, qn2p, khp, klp, kn2p, tclsp, partp);
  k_final<<<32, 256, 0, stream>>>(partp, out);
}